// Round 5
// baseline (382.209 us; speedup 1.0000x reference)
//
#include <hip/hip_runtime.h>
#include <math.h>

typedef float4 f4;
typedef __attribute__((ext_vector_type(4))) float f32x4;
typedef __attribute__((ext_vector_type(8))) short short8;
typedef __attribute__((ext_vector_type(4))) unsigned short u16x4;

static constexpr int kB  = 8;
static constexpr int kT  = 4096;
static constexpr int kD  = 1024;
static constexpr int kH  = 64;
static constexpr int kC  = 64;            // chunk length
static constexpr int kNC = kT / kC;       // 64 chunks per batch
static constexpr long kBT = (long)kB * kT;

__device__ __forceinline__ float phi_f(float x) {
    return x > 0.0f ? x + 1.0f : __expf(x);
}

__device__ __forceinline__ unsigned short f2bf(float f) {
    unsigned int u = __float_as_uint(f);
    u += 0x7FFF + ((u >> 16) & 1);        // round-to-nearest-even
    return (unsigned short)(u >> 16);
}

typedef const __attribute__((address_space(1))) unsigned int gu32;
typedef __attribute__((address_space(3))) unsigned int lu32;
#define GLL16(SRC, DST) __builtin_amdgcn_global_load_lds((gu32*)(SRC), (lu32*)(DST), 16, 0, 0)

#define LD4F(dst, src) { f4 _t_ = *(const f4*)(src); (dst)[0]=_t_.x; (dst)[1]=_t_.y; (dst)[2]=_t_.z; (dst)[3]=_t_.w; }

// ---------------------------------------------------------------------------
// K0: weight prep.  Wt[n=mat*64+nn][k] = W_mat[k][nn] (bf16, 192x1024)
//     Wot[n][k] = Wo[k][n]             (bf16, 1024x64)
// ---------------------------------------------------------------------------
__global__ __launch_bounds__(256)
void k0_prep(const float* __restrict__ Wq, const float* __restrict__ Wk,
             const float* __restrict__ Wv, const float* __restrict__ Wo,
             unsigned short* __restrict__ Wt, unsigned short* __restrict__ Wot)
{
    int g = blockIdx.x * 256 + threadIdx.x;
    if (g < 12288) {                       // 192 n-rows x 64 chunks of 16 k
        int n  = g >> 6;
        int kc = (g & 63) * 16;
        int mat = n >> 6, nn = n & 63;
        const float* W = (mat == 0) ? Wq : ((mat == 1) ? Wk : Wv);
        unsigned short* dst = Wt + (long)n * kD + kc;
        #pragma unroll
        for (int i = 0; i < 16; ++i) dst[i] = f2bf(W[(long)(kc + i) * kH + nn]);
    } else if (g < 12288 + 4096) {         // 1024 n-rows x 4 chunks of 16 k
        int g2 = g - 12288;
        int n  = g2 >> 2;
        int kc = (g2 & 3) * 16;
        unsigned short* dst = Wot + n * kH + kc;
        #pragma unroll
        for (int i = 0; i < 16; ++i) dst[i] = f2bf(Wo[(long)(kc + i) * kD + n]);
    }
}

// ---------------------------------------------------------------------------
// K1 (streaming rewrite): q = phi(x Wq), k = phi(x Wk), v = x Wv.
// bf16 MFMA 16x16x32, NO LDS, NO barriers. Each wave owns 16 rows x 192 cols.
// A-frag: lane l reads x[mb + w*16 + (l&15)][k0 + (l>>4)*8] (8 fp32 -> bf16);
//   lanes {l,l+16,l+32,l+48} of a row cover one full 128B line -> full coalesce.
// B-frag: lane l reads Wt[n*16 + (l&15)][k0 + (l>>4)*8] (16B); Wt is 384KB,
//   L2-resident. Latency hidden by ILP (unroll 4) + wave drift (no syncs).
// ---------------------------------------------------------------------------
__global__ __launch_bounds__(256, 2)
void k1_qkv_mfma(const float* __restrict__ x, const unsigned short* __restrict__ Wt,
                 float* __restrict__ q, float* __restrict__ k, float* __restrict__ v)
{
    const int t = threadIdx.x;
    const int w = t >> 6;
    const int l = t & 63;
    const long mb = (long)blockIdx.x * 64;

    const int  lrow = l & 15;           // fragment row-slice
    const int  kch  = (l >> 4) * 8;     // k-chunk offset (0,8,16,24)

    const float*          ap = x  + (mb + w * 16 + lrow) * kD + kch;
    const unsigned short* bp = Wt + (long)lrow * kD + kch;

    f32x4 acc[12];
    #pragma unroll
    for (int i = 0; i < 12; ++i) acc[i] = (f32x4){0.f, 0.f, 0.f, 0.f};

    #pragma unroll 4
    for (int k0 = 0; k0 < kD; k0 += 32) {
        f32x4 a0 = *(const f32x4*)(ap + k0);
        f32x4 a1 = *(const f32x4*)(ap + k0 + 4);
        short8 af;
        af[0] = (short)f2bf(a0[0]); af[1] = (short)f2bf(a0[1]);
        af[2] = (short)f2bf(a0[2]); af[3] = (short)f2bf(a0[3]);
        af[4] = (short)f2bf(a1[0]); af[5] = (short)f2bf(a1[1]);
        af[6] = (short)f2bf(a1[2]); af[7] = (short)f2bf(a1[3]);
        #pragma unroll
        for (int n16 = 0; n16 < 12; ++n16) {
            short8 bf = *(const short8*)(bp + (long)n16 * 16 * kD + k0);
            acc[n16] = __builtin_amdgcn_mfma_f32_16x16x32_bf16(af, bf, acc[n16], 0, 0, 0);
        }
    }

    // epilogue (verified): D row = (l>>4)*4 + reg, col = l&15
    const int om = (l >> 4) * 4;
    #pragma unroll
    for (int n16 = 0; n16 < 12; ++n16) {
        int mat = n16 >> 2;
        int col = (n16 & 3) * 16 + (l & 15);
        float* outp = (mat == 0) ? q : ((mat == 1) ? k : v);
        #pragma unroll
        for (int reg = 0; reg < 4; ++reg) {
            long row = mb + w * 16 + om + reg;
            float val = acc[n16][reg];
            if (mat < 2) val = phi_f(val);
            outp[row * kH + col] = val;
        }
    }
}

// ---------------------------------------------------------------------------
// K2: per-chunk state  Sc[i][j] = sum_tau k[tau][i] v[tau][j],  zc[i] = sum k.
// ---------------------------------------------------------------------------
__global__ __launch_bounds__(256)
void k2_state(const float* __restrict__ k, const float* __restrict__ v,
              float* __restrict__ Sc, float* __restrict__ zc)
{
    __shared__ float Ks2[64][64];
    __shared__ float Vs2[64][64];
    const int t = threadIdx.x;
    const long bc = blockIdx.x;
    const long rowbase = bc * kC;

    #pragma unroll
    for (int i = 0; i < 4; ++i) {
        int fi  = t + i * 256;
        int tau = fi >> 4;
        int cc  = (fi & 15) * 4;
        *(f4*)&Ks2[tau][cc] = *(const f4*)&k[(rowbase + tau) * kH + cc];
        *(f4*)&Vs2[tau][cc] = *(const f4*)&v[(rowbase + tau) * kH + cc];
    }
    __syncthreads();

    const int i  = t >> 2;
    const int j0 = (t & 3) * 16;
    float acc[16];
    #pragma unroll
    for (int c = 0; c < 16; ++c) acc[c] = 0.0f;
    float zacc = 0.0f;

    for (int tau = 0; tau < 64; ++tau) {
        float kv = Ks2[tau][i];
        zacc += kv;
        #pragma unroll
        for (int c = 0; c < 4; ++c) {
            float vv[4];
            LD4F(vv, &Vs2[tau][j0 + c * 4]);
            #pragma unroll
            for (int e = 0; e < 4; ++e) acc[c * 4 + e] += kv * vv[e];
        }
    }
    float* scp = Sc + bc * (kH * kH) + i * kH + j0;
    #pragma unroll
    for (int c = 0; c < 4; ++c) {
        f4 val; val.x = acc[c*4]; val.y = acc[c*4+1]; val.z = acc[c*4+2]; val.w = acc[c*4+3];
        *(f4*)&scp[c * 4] = val;
    }
    if ((t & 3) == 0) zc[bc * kH + i] = zacc;
}

// ---------------------------------------------------------------------------
// K3: exclusive prefix over chunks.
// ---------------------------------------------------------------------------
__global__ __launch_bounds__(256)
void k3_prefix(const float* __restrict__ Sc, float* __restrict__ Sp,
               const float* __restrict__ zc, float* __restrict__ zp)
{
    const int t = threadIdx.x;
    const int blk = blockIdx.x;
    if (blk < 128) {
        int g = blk * 256 + t;
        int b = g >> 12;
        int rem = g & 4095;
        const float* src = Sc + (long)b * kNC * kH * kH + rem;
        float*       dst = Sp + (long)b * kNC * kH * kH + rem;
        float vals[kNC];
        #pragma unroll
        for (int c = 0; c < kNC; ++c) vals[c] = src[c * (kH * kH)];
        float run = 0.0f;
        #pragma unroll
        for (int c = 0; c < kNC; ++c) { float nv = vals[c]; vals[c] = run; run += nv; }
        #pragma unroll
        for (int c = 0; c < kNC; ++c) dst[c * (kH * kH)] = vals[c];
    } else {
        int g = (blk - 128) * 256 + t;
        int b = g >> 6;
        int i = g & 63;
        const float* src = zc + (long)b * kNC * kH + i;
        float*       dst = zp + (long)b * kNC * kH + i;
        float vals[kNC];
        #pragma unroll
        for (int c = 0; c < kNC; ++c) vals[c] = src[c * kH];
        float run = 0.0f;
        #pragma unroll
        for (int c = 0; c < kNC; ++c) { float nv = vals[c]; vals[c] = run; run += nv; }
        #pragma unroll
        for (int c = 0; c < kNC; ++c) dst[c * kH] = vals[c];
    }
}

// ---------------------------------------------------------------------------
// K4: per-chunk output (unchanged algebra); emits o in bf16.
// ---------------------------------------------------------------------------
__global__ __launch_bounds__(256)
void k4_chunkout(const float* __restrict__ q, const float* __restrict__ k,
                 const float* __restrict__ v, const float* __restrict__ Sp,
                 const float* __restrict__ zp, unsigned short* __restrict__ o)
{
    __shared__ float QT[64 * 64];
    __shared__ float KsS[64 * 64];
    __shared__ float VT[64 * 64];
    __shared__ float zps[64];
    __shared__ float ds[64];

    const int t = threadIdx.x;
    const long bc = blockIdx.x;
    const long rowbase = bc * kC;

    #pragma unroll
    for (int ii = 0; ii < 4; ++ii) {
        int fi  = t + ii * 256;
        int tau = fi >> 4;
        int c4  = fi & 15;
        f4 qv = *(const f4*)&q[(rowbase + tau) * kH + c4 * 4];
        QT[(c4 * 4 + 0) * 64 + tau] = qv.x;
        QT[(c4 * 4 + 1) * 64 + tau] = qv.y;
        QT[(c4 * 4 + 2) * 64 + tau] = qv.z;
        QT[(c4 * 4 + 3) * 64 + tau] = qv.w;
        f4 vv = *(const f4*)&v[(rowbase + tau) * kH + c4 * 4];
        VT[(c4 * 4 + 0) * 64 + tau] = vv.x;
        VT[(c4 * 4 + 1) * 64 + tau] = vv.y;
        VT[(c4 * 4 + 2) * 64 + tau] = vv.z;
        VT[(c4 * 4 + 3) * 64 + tau] = vv.w;
        f4 kv = *(const f4*)&k[(rowbase + tau) * kH + c4 * 4];
        *(f4*)&KsS[tau * 64 + 4 * (c4 ^ (tau & 15))] = kv;
    }
    if (t < 16) {
        *(f4*)&zps[t * 4] = *(const f4*)&zp[bc * kH + t * 4];
    }
    __syncthreads();

    const int tg   = t & 15;
    const int ig   = t >> 4;
    const int tau0 = tg * 4;
    const int ip0  = ig * 4;

    float pv[4][4];
    #pragma unroll
    for (int a = 0; a < 4; ++a)
        #pragma unroll
        for (int b2 = 0; b2 < 4; ++b2) pv[a][b2] = 0.0f;
    for (int xx = 0; xx < 64; ++xx) {
        float q4[4], v4[4];
        LD4F(q4, &QT[xx * 64 + tau0]);
        LD4F(v4, &VT[xx * 64 + ip0]);
        #pragma unroll
        for (int e1 = 0; e1 < 4; ++e1)
            #pragma unroll
            for (int e0 = 0; e0 < 4; ++e0) pv[e1][e0] += v4[e1] * q4[e0];
    }
    __syncthreads();
    #pragma unroll
    for (int e1 = 0; e1 < 4; ++e1) {
        int tp = ip0 + e1;
        f4 w;
        w.x = (tp <= tau0 + 0) ? pv[e1][0] : 0.0f;
        w.y = (tp <= tau0 + 1) ? pv[e1][1] : 0.0f;
        w.z = (tp <= tau0 + 2) ? pv[e1][2] : 0.0f;
        w.w = (tp <= tau0 + 3) ? pv[e1][3] : 0.0f;
        *(f4*)&VT[tp * 64 + tau0] = w;
    }
    __syncthreads();

    float acc[4][4];
    #pragma unroll
    for (int a = 0; a < 4; ++a)
        #pragma unroll
        for (int b2 = 0; b2 < 4; ++b2) acc[a][b2] = 0.0f;
    for (int tp = 0; tp < 64; ++tp) {
        float p4[4], k4[4];
        LD4F(p4, &VT[tp * 64 + tau0]);
        LD4F(k4, &KsS[tp * 64 + 4 * (ig ^ (tp & 15))]);
        #pragma unroll
        for (int e0 = 0; e0 < 4; ++e0)
            #pragma unroll
            for (int e1 = 0; e1 < 4; ++e1) acc[e0][e1] += p4[e0] * k4[e1];
    }
    __syncthreads();

    #pragma unroll
    for (int ii = 0; ii < 4; ++ii) {
        int fi = t + ii * 256;
        int ir = fi >> 4;
        int j4 = fi & 15;
        f4 sv = *(const f4*)&Sp[bc * (kH * kH) + ir * kH + j4 * 4];
        VT[(j4 * 4 + 0) * 64 + ir] = sv.x;
        VT[(j4 * 4 + 1) * 64 + ir] = sv.y;
        VT[(j4 * 4 + 2) * 64 + ir] = sv.z;
        VT[(j4 * 4 + 3) * 64 + ir] = sv.w;
    }
    if (t < 64) {
        float run = 0.0f;
        const int jc4 = t >> 2, jr = t & 3;
        for (int tau = 0; tau < 64; ++tau) {
            int idx = tau * 64 + 4 * (jc4 ^ (tau & 15)) + jr;
            run += KsS[idx];
            KsS[idx] = run;
        }
    }
    __syncthreads();

    if (t < 64) {
        float dacc = 0.0f;
        for (int j = 0; j < 64; ++j) {
            float qv = QT[j * 64 + t];
            float ck = KsS[t * 64 + 4 * ((j >> 2) ^ (t & 15)) + (j & 3)];
            dacc += qv * (ck + zps[j]);
        }
        ds[t] = 1.0f / fmaxf(dacc, 1e-6f);
    }

    for (int j = 0; j < 64; ++j) {
        float q4[4], s4[4];
        LD4F(q4, &QT[j * 64 + tau0]);
        LD4F(s4, &VT[j * 64 + ip0]);
        #pragma unroll
        for (int e0 = 0; e0 < 4; ++e0)
            #pragma unroll
            for (int e1 = 0; e1 < 4; ++e1) acc[e0][e1] += q4[e0] * s4[e1];
    }
    __syncthreads();

    #pragma unroll
    for (int e0 = 0; e0 < 4; ++e0) {
        float inv = ds[tau0 + e0];
        u16x4 wv;
        wv[0] = f2bf(acc[e0][0] * inv);
        wv[1] = f2bf(acc[e0][1] * inv);
        wv[2] = f2bf(acc[e0][2] * inv);
        wv[3] = f2bf(acc[e0][3] * inv);
        *(u16x4*)&o[(rowbase + tau0 + e0) * kH + ip0] = wv;
    }
}

// ---------------------------------------------------------------------------
// K5: out = o @ Wo via bf16 MFMA.  BM=128, BN=128, K=64 (single pass).
// Both tiles via global_load_lds (pre-swizzled src). grid 256x8.
// ---------------------------------------------------------------------------
__global__ __launch_bounds__(256, 4)
void k5_outproj_mfma(const unsigned short* __restrict__ o,
                     const unsigned short* __restrict__ Wot,
                     float* __restrict__ out)
{
    __shared__ unsigned short Os[128 * 64];
    __shared__ unsigned short Ws5[128 * 64];
    const int t = threadIdx.x;
    const int w = t >> 6, l = t & 63;
    const int wm = w >> 1, wn = w & 1;
    const int mb = blockIdx.x >> 3;
    const int nb = blockIdx.x & 7;
    const long row0 = (long)mb * 128;
    const int  col0 = nb * 128;

    const int rin = l >> 3;      // 0..7 row within 8-row group
    const int cch = l & 7;       // chunk 0..7
    #pragma unroll
    for (int c = 0; c < 4; ++c) {
        int r = (c * 4 + w) * 8 + rin;                 // 0..127
        int g = cch ^ (r & 7);
        GLL16(o   + (row0 + r) * kH + g * 8,        Os  + (c * 4 + w) * 512);
        GLL16(Wot + (long)(col0 + r) * kH + g * 8,  Ws5 + (c * 4 + w) * 512);
    }
    __syncthreads();

    short8 af[4][2];
    #pragma unroll
    for (int mf = 0; mf < 4; ++mf) {
        int ar = wm * 64 + mf * 16 + (l & 15);
        #pragma unroll
        for (int ks = 0; ks < 2; ++ks)
            af[mf][ks] = *(const short8*)(Os + ar * 64 + (((ks * 4 + (l >> 4)) ^ (ar & 7)) * 8));
    }

    f32x4 acc[4][4];
    #pragma unroll
    for (int a = 0; a < 4; ++a)
        #pragma unroll
        for (int b2 = 0; b2 < 4; ++b2) acc[a][b2] = (f32x4){0.f, 0.f, 0.f, 0.f};

    #pragma unroll
    for (int nf = 0; nf < 4; ++nf) {
        int br = wn * 64 + nf * 16 + (l & 15);
        short8 bf0 = *(const short8*)(Ws5 + br * 64 + ((((l >> 4)) ^ (br & 7)) * 8));
        short8 bf1 = *(const short8*)(Ws5 + br * 64 + (((4 + (l >> 4)) ^ (br & 7)) * 8));
        #pragma unroll
        for (int mf = 0; mf < 4; ++mf) {
            acc[mf][nf] = __builtin_amdgcn_mfma_f32_16x16x32_bf16(af[mf][0], bf0, acc[mf][nf], 0, 0, 0);
            acc[mf][nf] = __builtin_amdgcn_mfma_f32_16x16x32_bf16(af[mf][1], bf1, acc[mf][nf], 0, 0, 0);
        }
    }

    #pragma unroll
    for (int mf = 0; mf < 4; ++mf)
        #pragma unroll
        for (int nf = 0; nf < 4; ++nf) {
            #pragma unroll
            for (int reg = 0; reg < 4; ++reg) {
                long row = row0 + wm * 64 + mf * 16 + (l >> 4) * 4 + reg;
                int  col = col0 + wn * 64 + nf * 16 + (l & 15);
                out[row * kD + col] = acc[mf][nf][reg];
            }
        }
}

// ---------------------------------------------------------------------------
extern "C" void kernel_launch(void* const* d_in, const int* in_sizes, int n_in,
                              void* d_out, int out_size, void* d_ws, size_t ws_size,
                              hipStream_t stream)
{
    const float* x  = (const float*)d_in[0];
    const float* Wq = (const float*)d_in[1];
    const float* Wk = (const float*)d_in[2];
    const float* Wv = (const float*)d_in[3];
    const float* Wo = (const float*)d_in[4];
    float* out = (float*)d_out;
    float* ws  = (float*)d_ws;

    const long NQ = kBT * kH;                     // 2097152
    float* q  = ws;
    float* k  = ws + NQ;
    float* v  = ws + 2 * NQ;
    float* Sc = ws + 3 * NQ;
    float* Sp = ws + 4 * NQ;
    unsigned short* obf = (unsigned short*)(ws + 5 * NQ);        // NQ bf16
    float* zc = ws + 5 * NQ + NQ / 2;
    float* zp = zc + (long)kB * kNC * kH;
    unsigned short* Wt  = (unsigned short*)(zp + (long)kB * kNC * kH);  // 192*1024
    unsigned short* Wot = Wt + 192 * 1024;                              // 1024*64

    k0_prep<<<64, 256, 0, stream>>>(Wq, Wk, Wv, Wo, Wt, Wot);
    k1_qkv_mfma<<<512, 256, 0, stream>>>(x, Wt, q, k, v);
    k2_state<<<kB * kNC, 256, 0, stream>>>(k, v, Sc, zc);
    k3_prefix<<<130, 256, 0, stream>>>(Sc, Sp, zc, zp);
    k4_chunkout<<<kB * kNC, 256, 0, stream>>>(q, k, v, Sp, zp, obf);
    k5_outproj_mfma<<<2048, 256, 0, stream>>>(obf, Wot, out);
}

// Round 9
// 307.280 us; speedup vs baseline: 1.2438x; 1.2438x over previous
//
#include <hip/hip_runtime.h>
#include <math.h>

typedef float4 f4;
typedef __attribute__((ext_vector_type(4))) float f32x4;
typedef __attribute__((ext_vector_type(8))) short short8;
typedef __attribute__((ext_vector_type(4))) unsigned short u16x4;

static constexpr int kB  = 8;
static constexpr int kT  = 4096;
static constexpr int kD  = 1024;
static constexpr int kH  = 64;
static constexpr int kC  = 64;            // chunk length
static constexpr int kNC = kT / kC;       // 64 chunks per batch
static constexpr long kBT = (long)kB * kT;

__device__ __forceinline__ float phi_f(float x) {
    return x > 0.0f ? x + 1.0f : __expf(x);
}

__device__ __forceinline__ unsigned short f2bf(float f) {
    unsigned int u = __float_as_uint(f);
    u += 0x7FFF + ((u >> 16) & 1);        // round-to-nearest-even
    return (unsigned short)(u >> 16);
}

typedef const __attribute__((address_space(1))) unsigned int gu32;
typedef __attribute__((address_space(3))) unsigned int lu32;
#define GLL16(SRC, DST) __builtin_amdgcn_global_load_lds((gu32*)(SRC), (lu32*)(DST), 16, 0, 0)

#define LD4F(dst, src) { f4 _t_ = *(const f4*)(src); (dst)[0]=_t_.x; (dst)[1]=_t_.y; (dst)[2]=_t_.z; (dst)[3]=_t_.w; }

// ---------------------------------------------------------------------------
// K0: weight prep.
//  Wg: K-tiled bf16 image of W_{q,k,v}^T matching k1's LDS layout exactly:
//    Wg[((kt*4 + c)*192 + r)*8 + e] = W_mat[kt*32 + c*8 + e][nn]
//    (r = mat*64+nn).  One K-tile (kt) = 6144 elems = 12KB, linearly copyable.
//  Wot[n][k] = Wo[k][n]  (bf16, 1024x64) for k5.
// ---------------------------------------------------------------------------
__global__ __launch_bounds__(256)
void k0_prep(const float* __restrict__ Wq, const float* __restrict__ Wk,
             const float* __restrict__ Wv, const float* __restrict__ Wo,
             unsigned short* __restrict__ Wg, unsigned short* __restrict__ Wot)
{
    int g = blockIdx.x * 256 + threadIdx.x;
    if (g < 24576) {                       // 32 kt x 4 c x 192 r
        int r   = g % 192;
        int rem = g / 192;
        int c   = rem & 3;
        int kt  = rem >> 2;
        int mat = r >> 6, nn = r & 63;
        const float* W = (mat == 0) ? Wq : ((mat == 1) ? Wk : Wv);
        int kbase = kt * 32 + c * 8;
        unsigned short* dst = Wg + (long)g * 8;
        #pragma unroll
        for (int e = 0; e < 8; ++e) dst[e] = f2bf(W[(long)(kbase + e) * kH + nn]);
    } else if (g < 24576 + 4096) {         // 1024 n-rows x 4 chunks of 16 k
        int g2 = g - 24576;
        int n  = g2 >> 2;
        int kc = (g2 & 3) * 16;
        unsigned short* dst = Wot + n * kH + kc;
        #pragma unroll
        for (int i = 0; i < 16; ++i) dst[i] = f2bf(Wo[(long)(kc + i) * kD + n]);
    }
}

// ---------------------------------------------------------------------------
// K1 (2-phase double-buffered): q = phi(x Wq), k = phi(x Wk), v = x Wv.
// bf16 MFMA 16x16x32.  BM=64, BK=32, 4 waves, grid 512.
// B: global_load_lds from pre-tiled Wg (linear 1KB/wave copies -> coalesced
//    src + conflict-free [c][192][8] LDS reads).
// A: reg-prefetch fp32 -> cvt bf16 -> ds_write into [c][64][8].
// One __syncthreads per K-step; next tile's loads issued BEFORE compute so
// their latency hides under ds_read+MFMA (T3 minimum 2-phase).
// ---------------------------------------------------------------------------
__global__ __launch_bounds__(256, 2)
void k1_qkv_mfma(const float* __restrict__ x, const unsigned short* __restrict__ Wg,
                 float* __restrict__ q, float* __restrict__ k, float* __restrict__ v)
{
    __shared__ unsigned short Bs[2][6144];   // [buf][c*192*8 + r*8 + e]
    __shared__ unsigned short As[2][2048];   // [buf][c*64*8 + row*8 + e]

    const int t = threadIdx.x;
    const int w = t >> 6;
    const int l = t & 63;
    const long mb = (long)blockIdx.x * 64;

    // A staging map: thread t -> row t>>2, k-chunk t&3 (32B global read)
    const int arow = t >> 2;
    const int ac   = t & 3;
    const float* ap = x + (mb + arow) * kD + ac * 8;
    const int awoff = (ac * 64 + arow) * 8;   // elem offset in As buffer

    // fragment read coords
    const int fc = l >> 4;            // k-chunk 0..3
    const int fr = l & 15;            // row-slice

    f32x4 acc[12];
    #pragma unroll
    for (int i = 0; i < 12; ++i) acc[i] = (f32x4){0.f, 0.f, 0.f, 0.f};

    // ---- prologue: stage tile 0, prefetch A regs for tile 1 ----
    #pragma unroll
    for (int c3 = 0; c3 < 3; ++c3) {
        int idx = w * 3 + c3;
        GLL16(Wg + idx * 512 + l * 8, &Bs[0][idx * 512]);
    }
    f32x4 a0 = *(const f32x4*)ap;
    f32x4 a1 = *(const f32x4*)(ap + 4);
    {
        short8 ab;
        ab[0] = (short)f2bf(a0[0]); ab[1] = (short)f2bf(a0[1]);
        ab[2] = (short)f2bf(a0[2]); ab[3] = (short)f2bf(a0[3]);
        ab[4] = (short)f2bf(a1[0]); ab[5] = (short)f2bf(a1[1]);
        ab[6] = (short)f2bf(a1[2]); ab[7] = (short)f2bf(a1[3]);
        *(short8*)&As[0][awoff] = ab;
    }
    a0 = *(const f32x4*)(ap + 32);
    a1 = *(const f32x4*)(ap + 36);
    __syncthreads();

    // ---- main loop: 32 K-steps ----
    for (int kt = 0; kt < 32; ++kt) {
        const int cur = kt & 1, nxt = cur ^ 1;
        if (kt + 1 < 32) {
            // issue next B tile (stays in flight across the compute below)
            #pragma unroll
            for (int c3 = 0; c3 < 3; ++c3) {
                int idx = w * 3 + c3;
                GLL16(Wg + (long)(kt + 1) * 6144 + idx * 512 + l * 8, &Bs[nxt][idx * 512]);
            }
            // write next A tile from prefetched regs
            short8 ab;
            ab[0] = (short)f2bf(a0[0]); ab[1] = (short)f2bf(a0[1]);
            ab[2] = (short)f2bf(a0[2]); ab[3] = (short)f2bf(a0[3]);
            ab[4] = (short)f2bf(a1[0]); ab[5] = (short)f2bf(a1[1]);
            ab[6] = (short)f2bf(a1[2]); ab[7] = (short)f2bf(a1[3]);
            *(short8*)&As[nxt][awoff] = ab;
            // prefetch A regs for tile kt+2
            if (kt + 2 < 32) {
                a0 = *(const f32x4*)(ap + (kt + 2) * 32);
                a1 = *(const f32x4*)(ap + (kt + 2) * 32 + 4);
            }
        }
        // compute current tile
        short8 af = *(const short8*)&As[cur][(fc * 64 + w * 16 + fr) * 8];
        #pragma unroll
        for (int n16 = 0; n16 < 12; ++n16) {
            short8 bf = *(const short8*)&Bs[cur][(fc * 192 + n16 * 16 + fr) * 8];
            acc[n16] = __builtin_amdgcn_mfma_f32_16x16x32_bf16(af, bf, acc[n16], 0, 0, 0);
        }
        __syncthreads();
    }

    // epilogue (verified): D row = (l>>4)*4 + reg, col = l&15
    const int om = (l >> 4) * 4;
    #pragma unroll
    for (int n16 = 0; n16 < 12; ++n16) {
        int mat = n16 >> 2;
        int col = (n16 & 3) * 16 + (l & 15);
        float* outp = (mat == 0) ? q : ((mat == 1) ? k : v);
        #pragma unroll
        for (int reg = 0; reg < 4; ++reg) {
            long row = mb + w * 16 + om + reg;
            float val = acc[n16][reg];
            if (mat < 2) val = phi_f(val);
            outp[row * kH + col] = val;
        }
    }
}

// ---------------------------------------------------------------------------
// K2: per-chunk state  Sc[i][j] = sum_tau k[tau][i] v[tau][j],  zc[i] = sum k.
// ---------------------------------------------------------------------------
__global__ __launch_bounds__(256)
void k2_state(const float* __restrict__ k, const float* __restrict__ v,
              float* __restrict__ Sc, float* __restrict__ zc)
{
    __shared__ float Ks2[64][64];
    __shared__ float Vs2[64][64];
    const int t = threadIdx.x;
    const long bc = blockIdx.x;
    const long rowbase = bc * kC;

    #pragma unroll
    for (int i = 0; i < 4; ++i) {
        int fi  = t + i * 256;
        int tau = fi >> 4;
        int cc  = (fi & 15) * 4;
        *(f4*)&Ks2[tau][cc] = *(const f4*)&k[(rowbase + tau) * kH + cc];
        *(f4*)&Vs2[tau][cc] = *(const f4*)&v[(rowbase + tau) * kH + cc];
    }
    __syncthreads();

    const int i  = t >> 2;
    const int j0 = (t & 3) * 16;
    float acc[16];
    #pragma unroll
    for (int c = 0; c < 16; ++c) acc[c] = 0.0f;
    float zacc = 0.0f;

    for (int tau = 0; tau < 64; ++tau) {
        float kv = Ks2[tau][i];
        zacc += kv;
        #pragma unroll
        for (int c = 0; c < 4; ++c) {
            float vv[4];
            LD4F(vv, &Vs2[tau][j0 + c * 4]);
            #pragma unroll
            for (int e = 0; e < 4; ++e) acc[c * 4 + e] += kv * vv[e];
        }
    }
    float* scp = Sc + bc * (kH * kH) + i * kH + j0;
    #pragma unroll
    for (int c = 0; c < 4; ++c) {
        f4 val; val.x = acc[c*4]; val.y = acc[c*4+1]; val.z = acc[c*4+2]; val.w = acc[c*4+3];
        *(f4*)&scp[c * 4] = val;
    }
    if ((t & 3) == 0) zc[bc * kH + i] = zacc;
}

// ---------------------------------------------------------------------------
// K3: exclusive prefix over chunks.
// ---------------------------------------------------------------------------
__global__ __launch_bounds__(256)
void k3_prefix(const float* __restrict__ Sc, float* __restrict__ Sp,
               const float* __restrict__ zc, float* __restrict__ zp)
{
    const int t = threadIdx.x;
    const int blk = blockIdx.x;
    if (blk < 128) {
        int g = blk * 256 + t;
        int b = g >> 12;
        int rem = g & 4095;
        const float* src = Sc + (long)b * kNC * kH * kH + rem;
        float*       dst = Sp + (long)b * kNC * kH * kH + rem;
        float vals[kNC];
        #pragma unroll
        for (int c = 0; c < kNC; ++c) vals[c] = src[c * (kH * kH)];
        float run = 0.0f;
        #pragma unroll
        for (int c = 0; c < kNC; ++c) { float nv = vals[c]; vals[c] = run; run += nv; }
        #pragma unroll
        for (int c = 0; c < kNC; ++c) dst[c * (kH * kH)] = vals[c];
    } else {
        int g = (blk - 128) * 256 + t;
        int b = g >> 6;
        int i = g & 63;
        const float* src = zc + (long)b * kNC * kH + i;
        float*       dst = zp + (long)b * kNC * kH + i;
        float vals[kNC];
        #pragma unroll
        for (int c = 0; c < kNC; ++c) vals[c] = src[c * kH];
        float run = 0.0f;
        #pragma unroll
        for (int c = 0; c < kNC; ++c) { float nv = vals[c]; vals[c] = run; run += nv; }
        #pragma unroll
        for (int c = 0; c < kNC; ++c) dst[c * kH] = vals[c];
    }
}

// ---------------------------------------------------------------------------
// K4: per-chunk output (unchanged algebra); emits o in bf16.
// ---------------------------------------------------------------------------
__global__ __launch_bounds__(256)
void k4_chunkout(const float* __restrict__ q, const float* __restrict__ k,
                 const float* __restrict__ v, const float* __restrict__ Sp,
                 const float* __restrict__ zp, unsigned short* __restrict__ o)
{
    __shared__ float QT[64 * 64];
    __shared__ float KsS[64 * 64];
    __shared__ float VT[64 * 64];
    __shared__ float zps[64];
    __shared__ float ds[64];

    const int t = threadIdx.x;
    const long bc = blockIdx.x;
    const long rowbase = bc * kC;

    #pragma unroll
    for (int ii = 0; ii < 4; ++ii) {
        int fi  = t + ii * 256;
        int tau = fi >> 4;
        int c4  = fi & 15;
        f4 qv = *(const f4*)&q[(rowbase + tau) * kH + c4 * 4];
        QT[(c4 * 4 + 0) * 64 + tau] = qv.x;
        QT[(c4 * 4 + 1) * 64 + tau] = qv.y;
        QT[(c4 * 4 + 2) * 64 + tau] = qv.z;
        QT[(c4 * 4 + 3) * 64 + tau] = qv.w;
        f4 vv = *(const f4*)&v[(rowbase + tau) * kH + c4 * 4];
        VT[(c4 * 4 + 0) * 64 + tau] = vv.x;
        VT[(c4 * 4 + 1) * 64 + tau] = vv.y;
        VT[(c4 * 4 + 2) * 64 + tau] = vv.z;
        VT[(c4 * 4 + 3) * 64 + tau] = vv.w;
        f4 kv = *(const f4*)&k[(rowbase + tau) * kH + c4 * 4];
        *(f4*)&KsS[tau * 64 + 4 * (c4 ^ (tau & 15))] = kv;
    }
    if (t < 16) {
        *(f4*)&zps[t * 4] = *(const f4*)&zp[bc * kH + t * 4];
    }
    __syncthreads();

    const int tg   = t & 15;
    const int ig   = t >> 4;
    const int tau0 = tg * 4;
    const int ip0  = ig * 4;

    float pv[4][4];
    #pragma unroll
    for (int a = 0; a < 4; ++a)
        #pragma unroll
        for (int b2 = 0; b2 < 4; ++b2) pv[a][b2] = 0.0f;
    for (int xx = 0; xx < 64; ++xx) {
        float q4[4], v4[4];
        LD4F(q4, &QT[xx * 64 + tau0]);
        LD4F(v4, &VT[xx * 64 + ip0]);
        #pragma unroll
        for (int e1 = 0; e1 < 4; ++e1)
            #pragma unroll
            for (int e0 = 0; e0 < 4; ++e0) pv[e1][e0] += v4[e1] * q4[e0];
    }
    __syncthreads();
    #pragma unroll
    for (int e1 = 0; e1 < 4; ++e1) {
        int tp = ip0 + e1;
        f4 w;
        w.x = (tp <= tau0 + 0) ? pv[e1][0] : 0.0f;
        w.y = (tp <= tau0 + 1) ? pv[e1][1] : 0.0f;
        w.z = (tp <= tau0 + 2) ? pv[e1][2] : 0.0f;
        w.w = (tp <= tau0 + 3) ? pv[e1][3] : 0.0f;
        *(f4*)&VT[tp * 64 + tau0] = w;
    }
    __syncthreads();

    float acc[4][4];
    #pragma unroll
    for (int a = 0; a < 4; ++a)
        #pragma unroll
        for (int b2 = 0; b2 < 4; ++b2) acc[a][b2] = 0.0f;
    for (int tp = 0; tp < 64; ++tp) {
        float p4[4], k4[4];
        LD4F(p4, &VT[tp * 64 + tau0]);
        LD4F(k4, &KsS[tp * 64 + 4 * (ig ^ (tp & 15))]);
        #pragma unroll
        for (int e0 = 0; e0 < 4; ++e0)
            #pragma unroll
            for (int e1 = 0; e1 < 4; ++e1) acc[e0][e1] += p4[e0] * k4[e1];
    }
    __syncthreads();

    #pragma unroll
    for (int ii = 0; ii < 4; ++ii) {
        int fi = t + ii * 256;
        int ir = fi >> 4;
        int j4 = fi & 15;
        f4 sv = *(const f4*)&Sp[bc * (kH * kH) + ir * kH + j4 * 4];
        VT[(j4 * 4 + 0) * 64 + ir] = sv.x;
        VT[(j4 * 4 + 1) * 64 + ir] = sv.y;
        VT[(j4 * 4 + 2) * 64 + ir] = sv.z;
        VT[(j4 * 4 + 3) * 64 + ir] = sv.w;
    }
    if (t < 64) {
        float run = 0.0f;
        const int jc4 = t >> 2, jr = t & 3;
        for (int tau = 0; tau < 64; ++tau) {
            int idx = tau * 64 + 4 * (jc4 ^ (tau & 15)) + jr;
            run += KsS[idx];
            KsS[idx] = run;
        }
    }
    __syncthreads();

    if (t < 64) {
        float dacc = 0.0f;
        for (int j = 0; j < 64; ++j) {
            float qv = QT[j * 64 + t];
            float ck = KsS[t * 64 + 4 * ((j >> 2) ^ (t & 15)) + (j & 3)];
            dacc += qv * (ck + zps[j]);
        }
        ds[t] = 1.0f / fmaxf(dacc, 1e-6f);
    }

    for (int j = 0; j < 64; ++j) {
        float q4[4], s4[4];
        LD4F(q4, &QT[j * 64 + tau0]);
        LD4F(s4, &VT[j * 64 + ip0]);
        #pragma unroll
        for (int e0 = 0; e0 < 4; ++e0)
            #pragma unroll
            for (int e1 = 0; e1 < 4; ++e1) acc[e0][e1] += q4[e0] * s4[e1];
    }
    __syncthreads();

    #pragma unroll
    for (int e0 = 0; e0 < 4; ++e0) {
        float inv = ds[tau0 + e0];
        u16x4 wv;
        wv[0] = f2bf(acc[e0][0] * inv);
        wv[1] = f2bf(acc[e0][1] * inv);
        wv[2] = f2bf(acc[e0][2] * inv);
        wv[3] = f2bf(acc[e0][3] * inv);
        *(u16x4*)&o[(rowbase + tau0 + e0) * kH + ip0] = wv;
    }
}

// ---------------------------------------------------------------------------
// K5: out = o @ Wo via bf16 MFMA.  BM=128, BN=128, K=64 (single pass).
// ---------------------------------------------------------------------------
__global__ __launch_bounds__(256, 4)
void k5_outproj_mfma(const unsigned short* __restrict__ o,
                     const unsigned short* __restrict__ Wot,
                     float* __restrict__ out)
{
    __shared__ unsigned short Os[128 * 64];
    __shared__ unsigned short Ws5[128 * 64];
    const int t = threadIdx.x;
    const int w = t >> 6, l = t & 63;
    const int wm = w >> 1, wn = w & 1;
    const int mb = blockIdx.x >> 3;
    const int nb = blockIdx.x & 7;
    const long row0 = (long)mb * 128;
    const int  col0 = nb * 128;

    const int rin = l >> 3;      // 0..7 row within 8-row group
    const int cch = l & 7;       // chunk 0..7
    #pragma unroll
    for (int c = 0; c < 4; ++c) {
        int r = (c * 4 + w) * 8 + rin;                 // 0..127
        int g = cch ^ (r & 7);
        GLL16(o   + (row0 + r) * kH + g * 8,        Os  + (c * 4 + w) * 512);
        GLL16(Wot + (long)(col0 + r) * kH + g * 8,  Ws5 + (c * 4 + w) * 512);
    }
    __syncthreads();

    short8 af[4][2];
    #pragma unroll
    for (int mf = 0; mf < 4; ++mf) {
        int ar = wm * 64 + mf * 16 + (l & 15);
        #pragma unroll
        for (int ks = 0; ks < 2; ++ks)
            af[mf][ks] = *(const short8*)(Os + ar * 64 + (((ks * 4 + (l >> 4)) ^ (ar & 7)) * 8));
    }

    f32x4 acc[4][4];
    #pragma unroll
    for (int a = 0; a < 4; ++a)
        #pragma unroll
        for (int b2 = 0; b2 < 4; ++b2) acc[a][b2] = (f32x4){0.f, 0.f, 0.f, 0.f};

    #pragma unroll
    for (int nf = 0; nf < 4; ++nf) {
        int br = wn * 64 + nf * 16 + (l & 15);
        short8 bf0 = *(const short8*)(Ws5 + br * 64 + ((((l >> 4)) ^ (br & 7)) * 8));
        short8 bf1 = *(const short8*)(Ws5 + br * 64 + (((4 + (l >> 4)) ^ (br & 7)) * 8));
        #pragma unroll
        for (int mf = 0; mf < 4; ++mf) {
            acc[mf][nf] = __builtin_amdgcn_mfma_f32_16x16x32_bf16(af[mf][0], bf0, acc[mf][nf], 0, 0, 0);
            acc[mf][nf] = __builtin_amdgcn_mfma_f32_16x16x32_bf16(af[mf][1], bf1, acc[mf][nf], 0, 0, 0);
        }
    }

    #pragma unroll
    for (int mf = 0; mf < 4; ++mf)
        #pragma unroll
        for (int nf = 0; nf < 4; ++nf) {
            #pragma unroll
            for (int reg = 0; reg < 4; ++reg) {
                long row = row0 + wm * 64 + mf * 16 + (l >> 4) * 4 + reg;
                int  col = col0 + wn * 64 + nf * 16 + (l & 15);
                out[row * kD + col] = acc[mf][nf][reg];
            }
        }
}

// ---------------------------------------------------------------------------
extern "C" void kernel_launch(void* const* d_in, const int* in_sizes, int n_in,
                              void* d_out, int out_size, void* d_ws, size_t ws_size,
                              hipStream_t stream)
{
    const float* x  = (const float*)d_in[0];
    const float* Wq = (const float*)d_in[1];
    const float* Wk = (const float*)d_in[2];
    const float* Wv = (const float*)d_in[3];
    const float* Wo = (const float*)d_in[4];
    float* out = (float*)d_out;
    float* ws  = (float*)d_ws;

    const long NQ = kBT * kH;                     // 2097152
    float* q  = ws;
    float* k  = ws + NQ;
    float* v  = ws + 2 * NQ;
    float* Sc = ws + 3 * NQ;
    float* Sp = ws + 4 * NQ;
    unsigned short* obf = (unsigned short*)(ws + 5 * NQ);        // NQ bf16
    float* zc = ws + 5 * NQ + NQ / 2;
    float* zp = zc + (long)kB * kNC * kH;
    unsigned short* Wg  = (unsigned short*)(zp + (long)kB * kNC * kH);  // 192*1024
    unsigned short* Wot = Wg + 192 * 1024;                              // 1024*64

    k0_prep<<<112, 256, 0, stream>>>(Wq, Wk, Wv, Wo, Wg, Wot);
    k1_qkv_mfma<<<512, 256, 0, stream>>>(x, Wg, q, k, v);
    k2_state<<<kB * kNC, 256, 0, stream>>>(k, v, Sc, zc);
    k3_prefix<<<130, 256, 0, stream>>>(Sc, Sp, zc, zp);
    k4_chunkout<<<kB * kNC, 256, 0, stream>>>(q, k, v, Sp, zp, obf);
    k5_outproj_mfma<<<2048, 256, 0, stream>>>(obf, Wot, out);
}

// Round 11
// 301.000 us; speedup vs baseline: 1.2698x; 1.0209x over previous
//
#include <hip/hip_runtime.h>
#include <math.h>

typedef float4 f4;
typedef __attribute__((ext_vector_type(4))) float f32x4;
typedef __attribute__((ext_vector_type(8))) short short8;
typedef __attribute__((ext_vector_type(8))) unsigned short u16x8;

static constexpr int kB  = 8;
static constexpr int kT  = 4096;
static constexpr int kD  = 1024;
static constexpr int kH  = 64;
static constexpr int kC  = 64;            // chunk length
static constexpr int kNC = kT / kC;       // 64 chunks per batch
static constexpr long kBT = (long)kB * kT;

__device__ __forceinline__ float phi_f(float x) {
    return x > 0.0f ? x + 1.0f : __expf(x);
}

__device__ __forceinline__ unsigned short f2bf(float f) {
    unsigned int u = __float_as_uint(f);
    u += 0x7FFF + ((u >> 16) & 1);        // round-to-nearest-even
    return (unsigned short)(u >> 16);
}

__device__ __forceinline__ float bf2f(unsigned short u) {
    return __uint_as_float((unsigned int)u << 16);
}

typedef const __attribute__((address_space(1))) unsigned int gu32;
typedef __attribute__((address_space(3))) unsigned int lu32;
#define GLL16(SRC, DST) __builtin_amdgcn_global_load_lds((gu32*)(SRC), (lu32*)(DST), 16, 0, 0)

#define LD4F(dst, src) { f4 _t_ = *(const f4*)(src); (dst)[0]=_t_.x; (dst)[1]=_t_.y; (dst)[2]=_t_.z; (dst)[3]=_t_.w; }

// ---------------------------------------------------------------------------
// K0: weight prep (unchanged).  Wg: K-tiled bf16 W_{q,k,v}^T image for k1;
// Wot[n][k] = Wo[k][n] bf16 for k5.
// ---------------------------------------------------------------------------
__global__ __launch_bounds__(256)
void k0_prep(const float* __restrict__ Wq, const float* __restrict__ Wk,
             const float* __restrict__ Wv, const float* __restrict__ Wo,
             unsigned short* __restrict__ Wg, unsigned short* __restrict__ Wot)
{
    int g = blockIdx.x * 256 + threadIdx.x;
    if (g < 24576) {                       // 32 kt x 4 c x 192 r
        int r   = g % 192;
        int rem = g / 192;
        int c   = rem & 3;
        int kt  = rem >> 2;
        int mat = r >> 6, nn = r & 63;
        const float* W = (mat == 0) ? Wq : ((mat == 1) ? Wk : Wv);
        int kbase = kt * 32 + c * 8;
        unsigned short* dst = Wg + (long)g * 8;
        #pragma unroll
        for (int e = 0; e < 8; ++e) dst[e] = f2bf(W[(long)(kbase + e) * kH + nn]);
    } else if (g < 24576 + 4096) {         // 1024 n-rows x 4 chunks of 16 k
        int g2 = g - 24576;
        int n  = g2 >> 2;
        int kc = (g2 & 3) * 16;
        unsigned short* dst = Wot + n * kH + kc;
        #pragma unroll
        for (int i = 0; i < 16; ++i) dst[i] = f2bf(Wo[(long)(kc + i) * kD + n]);
    }
}

// ---------------------------------------------------------------------------
// K1: q,k,v projections (2-phase dbuf MFMA, unchanged main loop).
// NEW epilogue: emits qb/kb/vb bf16 (+ k,v fp32 for k2) and per-chunk K^T
// (kTg[bc][i][tau], bf16) via padded-LDS transpose.  Block bc == chunk bc.
// ---------------------------------------------------------------------------
__global__ __launch_bounds__(256, 2)
void k1_qkv_mfma(const float* __restrict__ x, const unsigned short* __restrict__ Wg,
                 unsigned short* __restrict__ qb,
                 float* __restrict__ kf, unsigned short* __restrict__ kb,
                 float* __restrict__ vf, unsigned short* __restrict__ vb,
                 unsigned short* __restrict__ kTg)
{
    __shared__ unsigned short Bs[2][6144];   // [buf][c*192*8 + r*8 + e]
    __shared__ unsigned short As[2][2048];   // [buf][c*64*8 + row*8 + e]

    const int t = threadIdx.x;
    const int w = t >> 6;
    const int l = t & 63;
    const long mb = (long)blockIdx.x * 64;

    const int arow = t >> 2;
    const int ac   = t & 3;
    const float* ap = x + (mb + arow) * kD + ac * 8;
    const int awoff = (ac * 64 + arow) * 8;

    const int fc = l >> 4;
    const int fr = l & 15;

    f32x4 acc[12];
    #pragma unroll
    for (int i = 0; i < 12; ++i) acc[i] = (f32x4){0.f, 0.f, 0.f, 0.f};

    #pragma unroll
    for (int c3 = 0; c3 < 3; ++c3) {
        int idx = w * 3 + c3;
        GLL16(Wg + idx * 512 + l * 8, &Bs[0][idx * 512]);
    }
    f32x4 a0 = *(const f32x4*)ap;
    f32x4 a1 = *(const f32x4*)(ap + 4);
    {
        short8 ab;
        ab[0] = (short)f2bf(a0[0]); ab[1] = (short)f2bf(a0[1]);
        ab[2] = (short)f2bf(a0[2]); ab[3] = (short)f2bf(a0[3]);
        ab[4] = (short)f2bf(a1[0]); ab[5] = (short)f2bf(a1[1]);
        ab[6] = (short)f2bf(a1[2]); ab[7] = (short)f2bf(a1[3]);
        *(short8*)&As[0][awoff] = ab;
    }
    a0 = *(const f32x4*)(ap + 32);
    a1 = *(const f32x4*)(ap + 36);
    __syncthreads();

    for (int kt = 0; kt < 32; ++kt) {
        const int cur = kt & 1, nxt = cur ^ 1;
        if (kt + 1 < 32) {
            #pragma unroll
            for (int c3 = 0; c3 < 3; ++c3) {
                int idx = w * 3 + c3;
                GLL16(Wg + (long)(kt + 1) * 6144 + idx * 512 + l * 8, &Bs[nxt][idx * 512]);
            }
            short8 ab;
            ab[0] = (short)f2bf(a0[0]); ab[1] = (short)f2bf(a0[1]);
            ab[2] = (short)f2bf(a0[2]); ab[3] = (short)f2bf(a0[3]);
            ab[4] = (short)f2bf(a1[0]); ab[5] = (short)f2bf(a1[1]);
            ab[6] = (short)f2bf(a1[2]); ab[7] = (short)f2bf(a1[3]);
            *(short8*)&As[nxt][awoff] = ab;
            if (kt + 2 < 32) {
                a0 = *(const f32x4*)(ap + (kt + 2) * 32);
                a1 = *(const f32x4*)(ap + (kt + 2) * 32 + 4);
            }
        }
        short8 af = *(const short8*)&As[cur][(fc * 64 + w * 16 + fr) * 8];
        #pragma unroll
        for (int n16 = 0; n16 < 12; ++n16) {
            short8 bf = *(const short8*)&Bs[cur][(fc * 192 + n16 * 16 + fr) * 8];
            acc[n16] = __builtin_amdgcn_mfma_f32_16x16x32_bf16(af, bf, acc[n16], 0, 0, 0);
        }
        __syncthreads();
    }

    // ---- epilogue: D row=(l>>4)*4+reg, col=l&15 ----
    unsigned short* kTt = &Bs[0][0];   // scratch: [64 cols][72 pad] bf16
    const int om = (l >> 4) * 4;
    #pragma unroll
    for (int n16 = 0; n16 < 12; ++n16) {
        int mat = n16 >> 2;
        int col = (n16 & 3) * 16 + (l & 15);
        #pragma unroll
        for (int reg = 0; reg < 4; ++reg) {
            int  row  = w * 16 + om + reg;       // 0..63 (chunk-local)
            long grow = mb + row;
            float val = acc[n16][reg];
            if (mat < 2) val = phi_f(val);
            unsigned short bv = f2bf(val);
            if (mat == 0) {
                qb[grow * kH + col] = bv;
            } else if (mat == 1) {
                kf[grow * kH + col] = val;
                kb[grow * kH + col] = bv;
                kTt[col * 72 + row] = bv;        // transpose stage
            } else {
                vf[grow * kH + col] = val;
                vb[grow * kH + col] = bv;
            }
        }
    }
    __syncthreads();
    // write kTg[bc][i][tau] coalesced: thread t -> i = t>>2, 16 taus
    {
        int i = t >> 2, s = (t & 3) * 16;
        u16x8 h0 = *(const u16x8*)&kTt[i * 72 + s];
        u16x8 h1 = *(const u16x8*)&kTt[i * 72 + s + 8];
        unsigned short* dst = kTg + (long)blockIdx.x * 4096 + i * 64 + s;
        *(u16x8*)dst       = h0;
        *(u16x8*)(dst + 8) = h1;
    }
}

// ---------------------------------------------------------------------------
// K2: per-chunk state  Sc[i][j] = sum_tau k[tau][i] v[tau][j],  zc[i] = sum k.
// (unchanged, fp32 inputs)
// ---------------------------------------------------------------------------
__global__ __launch_bounds__(256)
void k2_state(const float* __restrict__ k, const float* __restrict__ v,
              float* __restrict__ Sc, float* __restrict__ zc)
{
    __shared__ float Ks2[64][64];
    __shared__ float Vs2[64][64];
    const int t = threadIdx.x;
    const long bc = blockIdx.x;
    const long rowbase = bc * kC;

    #pragma unroll
    for (int i = 0; i < 4; ++i) {
        int fi  = t + i * 256;
        int tau = fi >> 4;
        int cc  = (fi & 15) * 4;
        *(f4*)&Ks2[tau][cc] = *(const f4*)&k[(rowbase + tau) * kH + cc];
        *(f4*)&Vs2[tau][cc] = *(const f4*)&v[(rowbase + tau) * kH + cc];
    }
    __syncthreads();

    const int i  = t >> 2;
    const int j0 = (t & 3) * 16;
    float acc[16];
    #pragma unroll
    for (int c = 0; c < 16; ++c) acc[c] = 0.0f;
    float zacc = 0.0f;

    for (int tau = 0; tau < 64; ++tau) {
        float kv = Ks2[tau][i];
        zacc += kv;
        #pragma unroll
        for (int c = 0; c < 4; ++c) {
            float vv[4];
            LD4F(vv, &Vs2[tau][j0 + c * 4]);
            #pragma unroll
            for (int e = 0; e < 4; ++e) acc[c * 4 + e] += kv * vv[e];
        }
    }
    float* scp = Sc + bc * (kH * kH) + i * kH + j0;
    #pragma unroll
    for (int c = 0; c < 4; ++c) {
        f4 val; val.x = acc[c*4]; val.y = acc[c*4+1]; val.z = acc[c*4+2]; val.w = acc[c*4+3];
        *(f4*)&scp[c * 4] = val;
    }
    if ((t & 3) == 0) zc[bc * kH + i] = zacc;
}

// ---------------------------------------------------------------------------
// K3: exclusive prefix over chunks.  S-prefix now emitted as SPLIT-BF16
// (SpH + SpL, hi/lo residual) so k4 can MFMA it at ~fp32 precision.
// ---------------------------------------------------------------------------
__global__ __launch_bounds__(256)
void k3_prefix(const float* __restrict__ Sc,
               unsigned short* __restrict__ SpH, unsigned short* __restrict__ SpL,
               const float* __restrict__ zc, float* __restrict__ zp)
{
    const int t = threadIdx.x;
    const int blk = blockIdx.x;
    if (blk < 128) {
        int g = blk * 256 + t;
        int b = g >> 12;
        int rem = g & 4095;
        const float* src       = Sc  + (long)b * kNC * 4096 + rem;
        unsigned short* dh     = SpH + (long)b * kNC * 4096 + rem;
        unsigned short* dl     = SpL + (long)b * kNC * 4096 + rem;
        float vals[kNC];
        #pragma unroll
        for (int c = 0; c < kNC; ++c) vals[c] = src[c * 4096];
        float run = 0.0f;
        #pragma unroll
        for (int c = 0; c < kNC; ++c) { float nv = vals[c]; vals[c] = run; run += nv; }
        #pragma unroll
        for (int c = 0; c < kNC; ++c) {
            unsigned short h = f2bf(vals[c]);
            dh[c * 4096] = h;
            dl[c * 4096] = f2bf(vals[c] - bf2f(h));
        }
    } else {
        int g = (blk - 128) * 256 + t;
        int b = g >> 6;
        int i = g & 63;
        const float* src = zc + (long)b * kNC * kH + i;
        float*       dst = zp + (long)b * kNC * kH + i;
        float vals[kNC];
        #pragma unroll
        for (int c = 0; c < kNC; ++c) vals[c] = src[c * kH];
        float run = 0.0f;
        #pragma unroll
        for (int c = 0; c < kNC; ++c) { float nv = vals[c]; vals[c] = run; run += nv; }
        #pragma unroll
        for (int c = 0; c < kNC; ++c) dst[c * kH] = vals[c];
    }
}

// ---------------------------------------------------------------------------
// K4 (MFMA rewrite): per-chunk output.
//   S = Q K^T (masked) -> rowsum -> denominator (no serial cumsum)
//   P = Q V^T (masked) -> LDS bf16
//   O = P·KT + Q·(SpH+SpL)
//   d[tau] = rowsum(masked S) + q_tau · zp;  o = O / max(d,1e-6), bf16 out.
// 2 barriers, 40 MFMA/wave, all operands GLL-staged (linear, L2-hot).
// ---------------------------------------------------------------------------
__global__ __launch_bounds__(256, 2)
void k4_chunkout_mfma(const unsigned short* __restrict__ qb,
                      const unsigned short* __restrict__ kb,
                      const unsigned short* __restrict__ vb,
                      const unsigned short* __restrict__ kTg,
                      const unsigned short* __restrict__ SpH,
                      const unsigned short* __restrict__ SpL,
                      const float* __restrict__ zp,
                      unsigned short* __restrict__ o)
{
    __shared__ unsigned short Q[4096], K[4096], V[4096], KT[4096];
    __shared__ unsigned short SH[4096], SL[4096], Pl[4096];
    __shared__ float zps[64], qz[64];

    const int t = threadIdx.x;
    const int w = t >> 6, l = t & 63;
    const long bc = blockIdx.x;
    const long base = bc * 4096;

    // ---- stage all operands (linear GLL; each wave 2 chunks per array) ----
    #pragma unroll
    for (int j2 = 0; j2 < 2; ++j2) {
        int j = w * 2 + j2;
        int off = j * 512 + l * 8;
        GLL16(qb  + base + off, Q  + j * 512);
        GLL16(kb  + base + off, K  + j * 512);
        GLL16(vb  + base + off, V  + j * 512);
        GLL16(kTg + base + off, KT + j * 512);
        GLL16(SpH + base + off, SH + j * 512);
        GLL16(SpL + base + off, SL + j * 512);
    }
    if (t < 16) *(f4*)&zps[t * 4] = *(const f4*)&zp[bc * kH + t * 4];
    __syncthreads();

    const int fr = l & 15, fc = l >> 4;
    const int aoff = (w * 16 + fr) * 64 + fc * 8;    // A-frag elem base (row-major)

    // ---- S = Q K^T,  P = Q V^T ----
    f32x4 s_acc[4], p_acc[4];
    #pragma unroll
    for (int n16 = 0; n16 < 4; ++n16) {
        s_acc[n16] = (f32x4){0.f, 0.f, 0.f, 0.f};
        p_acc[n16] = (f32x4){0.f, 0.f, 0.f, 0.f};
    }
    #pragma unroll
    for (int k32 = 0; k32 < 2; ++k32) {
        short8 aq = *(const short8*)&Q[aoff + k32 * 32];
        #pragma unroll
        for (int n16 = 0; n16 < 4; ++n16) {
            int boff = (n16 * 16 + fr) * 64 + k32 * 32 + fc * 8;
            s_acc[n16] = __builtin_amdgcn_mfma_f32_16x16x32_bf16(
                aq, *(const short8*)&K[boff], s_acc[n16], 0, 0, 0);
            p_acc[n16] = __builtin_amdgcn_mfma_f32_16x16x32_bf16(
                aq, *(const short8*)&V[boff], p_acc[n16], 0, 0, 0);
        }
    }

    // ---- mask: keep col(tau') <= row(tau).  P -> LDS bf16; S -> rowsum ----
    float rsum[4] = {0.f, 0.f, 0.f, 0.f};
    #pragma unroll
    for (int n16 = 0; n16 < 4; ++n16) {
        int col = n16 * 16 + fr;
        #pragma unroll
        for (int reg = 0; reg < 4; ++reg) {
            int row = w * 16 + fc * 4 + reg;
            bool keep = (col <= row);
            Pl[row * 64 + col] = keep ? f2bf(p_acc[n16][reg]) : (unsigned short)0;
            if (keep) rsum[reg] += s_acc[n16][reg];
        }
    }
    #pragma unroll
    for (int reg = 0; reg < 4; ++reg) {          // reduce across the 16 col-lanes
        rsum[reg] += __shfl_xor(rsum[reg], 1);
        rsum[reg] += __shfl_xor(rsum[reg], 2);
        rsum[reg] += __shfl_xor(rsum[reg], 4);
        rsum[reg] += __shfl_xor(rsum[reg], 8);
    }
    // ---- qz[tau] = q_tau . zp  (one row per thread t<64) ----
    if (t < 64) {
        float accz = 0.0f;
        #pragma unroll 8
        for (int j = 0; j < 64; ++j) accz += bf2f(Q[t * 64 + j]) * zps[j];
        qz[t] = accz;
    }
    __syncthreads();

    // ---- O = P·KT + Q·SpH + Q·SpL ----
    f32x4 o_acc[4];
    #pragma unroll
    for (int n16 = 0; n16 < 4; ++n16) o_acc[n16] = (f32x4){0.f, 0.f, 0.f, 0.f};
    #pragma unroll
    for (int k32 = 0; k32 < 2; ++k32) {
        short8 ap = *(const short8*)&Pl[aoff + k32 * 32];
        short8 aq = *(const short8*)&Q[aoff + k32 * 32];
        #pragma unroll
        for (int n16 = 0; n16 < 4; ++n16) {
            int boff = (n16 * 16 + fr) * 64 + k32 * 32 + fc * 8;
            o_acc[n16] = __builtin_amdgcn_mfma_f32_16x16x32_bf16(
                ap, *(const short8*)&KT[boff], o_acc[n16], 0, 0, 0);
            o_acc[n16] = __builtin_amdgcn_mfma_f32_16x16x32_bf16(
                aq, *(const short8*)&SH[boff], o_acc[n16], 0, 0, 0);
            o_acc[n16] = __builtin_amdgcn_mfma_f32_16x16x32_bf16(
                aq, *(const short8*)&SL[boff], o_acc[n16], 0, 0, 0);
        }
    }

    // ---- normalize + write (same lanes hold d for their own D-rows) ----
    float invd[4];
    #pragma unroll
    for (int reg = 0; reg < 4; ++reg) {
        int row = w * 16 + fc * 4 + reg;
        invd[reg] = 1.0f / fmaxf(rsum[reg] + qz[row], 1e-6f);
    }
    const long rowg = bc * 64;
    #pragma unroll
    for (int n16 = 0; n16 < 4; ++n16) {
        int col = n16 * 16 + fr;
        #pragma unroll
        for (int reg = 0; reg < 4; ++reg) {
            int row = w * 16 + fc * 4 + reg;
            o[(rowg + row) * kH + col] = f2bf(o_acc[n16][reg] * invd[reg]);
        }
    }
}

// ---------------------------------------------------------------------------
// K5: out = o @ Wo via bf16 MFMA (unchanged).
// ---------------------------------------------------------------------------
__global__ __launch_bounds__(256, 4)
void k5_outproj_mfma(const unsigned short* __restrict__ o,
                     const unsigned short* __restrict__ Wot,
                     float* __restrict__ out)
{
    __shared__ unsigned short Os[128 * 64];
    __shared__ unsigned short Ws5[128 * 64];
    const int t = threadIdx.x;
    const int w = t >> 6, l = t & 63;
    const int wm = w >> 1, wn = w & 1;
    const int mb = blockIdx.x >> 3;
    const int nb = blockIdx.x & 7;
    const long row0 = (long)mb * 128;
    const int  col0 = nb * 128;

    const int rin = l >> 3;
    const int cch = l & 7;
    #pragma unroll
    for (int c = 0; c < 4; ++c) {
        int r = (c * 4 + w) * 8 + rin;
        int g = cch ^ (r & 7);
        GLL16(o   + (row0 + r) * kH + g * 8,        Os  + (c * 4 + w) * 512);
        GLL16(Wot + (long)(col0 + r) * kH + g * 8,  Ws5 + (c * 4 + w) * 512);
    }
    __syncthreads();

    short8 af[4][2];
    #pragma unroll
    for (int mf = 0; mf < 4; ++mf) {
        int ar = wm * 64 + mf * 16 + (l & 15);
        #pragma unroll
        for (int ks = 0; ks < 2; ++ks)
            af[mf][ks] = *(const short8*)(Os + ar * 64 + (((ks * 4 + (l >> 4)) ^ (ar & 7)) * 8));
    }

    f32x4 acc[4][4];
    #pragma unroll
    for (int a = 0; a < 4; ++a)
        #pragma unroll
        for (int b2 = 0; b2 < 4; ++b2) acc[a][b2] = (f32x4){0.f, 0.f, 0.f, 0.f};

    #pragma unroll
    for (int nf = 0; nf < 4; ++nf) {
        int br = wn * 64 + nf * 16 + (l & 15);
        short8 bf0 = *(const short8*)(Ws5 + br * 64 + ((((l >> 4)) ^ (br & 7)) * 8));
        short8 bf1 = *(const short8*)(Ws5 + br * 64 + (((4 + (l >> 4)) ^ (br & 7)) * 8));
        #pragma unroll
        for (int mf = 0; mf < 4; ++mf) {
            acc[mf][nf] = __builtin_amdgcn_mfma_f32_16x16x32_bf16(af[mf][0], bf0, acc[mf][nf], 0, 0, 0);
            acc[mf][nf] = __builtin_amdgcn_mfma_f32_16x16x32_bf16(af[mf][1], bf1, acc[mf][nf], 0, 0, 0);
        }
    }

    #pragma unroll
    for (int mf = 0; mf < 4; ++mf)
        #pragma unroll
        for (int nf = 0; nf < 4; ++nf) {
            #pragma unroll
            for (int reg = 0; reg < 4; ++reg) {
                long row = row0 + wm * 64 + mf * 16 + (l >> 4) * 4 + reg;
                int  col = col0 + wn * 64 + nf * 16 + (l & 15);
                out[row * kD + col] = acc[mf][nf][reg];
            }
        }
}

// ---------------------------------------------------------------------------
extern "C" void kernel_launch(void* const* d_in, const int* in_sizes, int n_in,
                              void* d_out, int out_size, void* d_ws, size_t ws_size,
                              hipStream_t stream)
{
    const float* x  = (const float*)d_in[0];
    const float* Wq = (const float*)d_in[1];
    const float* Wk = (const float*)d_in[2];
    const float* Wv = (const float*)d_in[3];
    const float* Wo = (const float*)d_in[4];
    float* out = (float*)d_out;
    float* ws  = (float*)d_ws;

    const long NQ = kBT * kH;                       // 2097152
    float* kf = ws;                                 // fp32 k (k2)
    float* vf = ws + NQ;                            // fp32 v (k2)
    float* Sc = ws + 2 * NQ;                        // chunk states fp32
    float* zc = ws + 3 * NQ;                        // 32768
    float* zp = zc + (long)kB * kNC * kH;           // 32768
    unsigned short* qb  = (unsigned short*)(zp + (long)kB * kNC * kH);
    unsigned short* kb  = qb  + NQ;
    unsigned short* vb  = kb  + NQ;
    unsigned short* kTg = vb  + NQ;
    unsigned short* SpH = kTg + NQ;
    unsigned short* SpL = SpH + NQ;
    unsigned short* obf = SpL + NQ;
    unsigned short* Wg  = obf + NQ;                 // 196608
    unsigned short* Wot = Wg + 192 * 1024;          // 65536

    k0_prep<<<112, 256, 0, stream>>>(Wq, Wk, Wv, Wo, Wg, Wot);
    k1_qkv_mfma<<<512, 256, 0, stream>>>(x, Wg, qb, kf, kb, vf, vb, kTg);
    k2_state<<<kB * kNC, 256, 0, stream>>>(kf, vf, Sc, zc);
    k3_prefix<<<130, 256, 0, stream>>>(Sc, SpH, SpL, zc, zp);
    k4_chunkout_mfma<<<kB * kNC, 256, 0, stream>>>(qb, kb, vb, kTg, SpH, SpL, zp, obf);
    k5_outproj_mfma<<<2048, 256, 0, stream>>>(obf, Wot, out);
}